// Round 1
// baseline (467.353 us; speedup 1.0000x reference)
//
#include <hip/hip_runtime.h>
#include <cmath>

#define Bsz 8
#define Csz 512
#define Lsz 4096
#define LPOOL 511
#define NEGV -1000000000.0f

// ---------------------------------------------------------------------------
// Kernel 0: detect mask element width. int32 {0,1} little-endian => every byte
// at position i%4!=0 is zero. uint8 {0,1} => ~half of those are 1.
__global__ void detect_mask(const unsigned char* __restrict__ mb, int* __restrict__ flag) {
  int f = 0;
  for (int i = 0; i < 1024; ++i) {
    if ((i & 3) && mb[i]) { f = 1; break; }
  }
  *flag = f;  // 0 = int32 mask, 1 = uint8 mask
}

// ---------------------------------------------------------------------------
// Kernel 1: s[b,l] = sum_d tanh( sum_c x[b,c,l]*W[d,c] + bias[d] ) * v[d]
// GEMM M=B*L, N=512(d), K=512(c), fused tanh + dot-with-v epilogue.
// Block: 256 threads, computes 64 l-positions x all 512 d (8 chunks of 64).
__global__ __launch_bounds__(256) void gemm_s(const float* __restrict__ x,
    const float* __restrict__ W, const float* __restrict__ bias,
    const float* __restrict__ v, float* __restrict__ s_out) {
  __shared__ float sA[32][64];   // [kc][m]  x tile
  __shared__ float sB[32][68];   // [kc][d]  W tile (+4 pad: b128-aligned, conflict-poor)
  __shared__ float s_acc[64];
  const int tid = threadIdx.x;
  const int b = blockIdx.y;
  const int l0 = blockIdx.x * 64;
  if (tid < 64) s_acc[tid] = 0.0f;
  const int tx = tid & 15;   // m group (4 m's)
  const int ty = tid >> 4;   // d group (4 d's)
  const float* xb = x + ((size_t)b * Csz) * Lsz + l0;

  for (int d0 = 0; d0 < Csz; d0 += 64) {
    float acc[4][4] = {{0.f}};
    for (int c0 = 0; c0 < Csz; c0 += 32) {
      __syncthreads();  // protect LDS from previous chunk's readers (and s_acc init)
      #pragma unroll
      for (int it = 0; it < 8; ++it) {
        int idx = tid + it * 256;
        int kc = idx >> 6, ml = idx & 63;
        sA[kc][ml] = xb[(size_t)(c0 + kc) * Lsz + ml];          // coalesced in l
      }
      #pragma unroll
      for (int it = 0; it < 8; ++it) {
        int idx = tid + it * 256;
        int kc = idx & 31, dj = idx >> 5;
        sB[kc][dj] = W[(size_t)(d0 + dj) * Csz + c0 + kc];      // coalesced in c
      }
      __syncthreads();
      #pragma unroll
      for (int kc = 0; kc < 32; ++kc) {
        float4 a  = *(const float4*)(&sA[kc][tx << 2]);
        float4 w4 = *(const float4*)(&sB[kc][ty << 2]);
        acc[0][0] += a.x * w4.x; acc[0][1] += a.x * w4.y; acc[0][2] += a.x * w4.z; acc[0][3] += a.x * w4.w;
        acc[1][0] += a.y * w4.x; acc[1][1] += a.y * w4.y; acc[1][2] += a.y * w4.z; acc[1][3] += a.y * w4.w;
        acc[2][0] += a.z * w4.x; acc[2][1] += a.z * w4.y; acc[2][2] += a.z * w4.z; acc[2][3] += a.z * w4.w;
        acc[3][0] += a.w * w4.x; acc[3][1] += a.w * w4.y; acc[3][2] += a.w * w4.z; acc[3][3] += a.w * w4.w;
      }
    }
    // epilogue for this d-chunk: tanh(+bias) * v, reduce over this thread's 4 d's
    float part[4] = {0.f, 0.f, 0.f, 0.f};
    #pragma unroll
    for (int j = 0; j < 4; ++j) {
      int d = d0 + (ty << 2) + j;
      float bj = bias[d], vj = v[d];
      #pragma unroll
      for (int i = 0; i < 4; ++i)
        part[i] += tanhf(acc[i][j] + bj) * vj;
    }
    #pragma unroll
    for (int i = 0; i < 4; ++i)
      atomicAdd(&s_acc[(tx << 2) + i], part[i]);
  }
  __syncthreads();
  if (tid < 64) s_out[(size_t)b * Lsz + l0 + tid] = s_acc[tid];
}

// ---------------------------------------------------------------------------
// Kernel 2: windowed masked softmax -> normalized weights wgt[b,p,w]
__global__ void win_weights(const float* __restrict__ s, const void* __restrict__ mask,
                            const int* __restrict__ flag, float* __restrict__ wgt) {
  int t = blockIdx.x * blockDim.x + threadIdx.x;
  if (t >= Bsz * LPOOL) return;
  int b = t / LPOOL, p = t - b * LPOOL;
  const bool u8 = (*flag != 0);
  const unsigned char* m8 = (const unsigned char*)mask;
  const int* m32 = (const int*)mask;
  float sv[16]; int mv[16];
  float mx = -3.4e38f;
  int base = b * Lsz + p * 8;
  #pragma unroll
  for (int w = 0; w < 16; ++w) {
    int mk = u8 ? (int)m8[base + w] : m32[base + w];
    float val = mk ? NEGV : s[base + w];
    sv[w] = val; mv[w] = mk;
    mx = fmaxf(mx, val);
  }
  float sum = 0.f;
  #pragma unroll
  for (int w = 0; w < 16; ++w) { sv[w] = expf(sv[w] - mx); sum += sv[w]; }
  float inv = 1.0f / sum;
  float norm = 0.f;
  #pragma unroll
  for (int w = 0; w < 16; ++w) { sv[w] = mv[w] ? 0.f : sv[w] * inv; norm += sv[w]; }
  norm = fmaxf(norm, 1e-6f);
  float rn = 1.0f / norm;
  #pragma unroll
  for (int w = 0; w < 16; ++w) wgt[t * 16 + w] = sv[w] * rn;
}

// ---------------------------------------------------------------------------
// Kernel 3: out[b,c,p] = sum_w x[b,c,8p+w] * wgt[b,p,w]. One block per (b,c).
__global__ __launch_bounds__(256) void pool_out(const float* __restrict__ x,
    const float* __restrict__ wgt, float* __restrict__ out) {
  __shared__ float xrow[Lsz];
  int bc = blockIdx.x;
  int c = bc & (Csz - 1);
  int b = bc >> 9;
  const float* xr = x + ((size_t)b * Csz + c) * Lsz;
  int tid = threadIdx.x;
  #pragma unroll
  for (int it = 0; it < 4; ++it) {
    int idx = (tid + it * 256) << 2;
    *(float4*)(&xrow[idx]) = *(const float4*)(&xr[idx]);
  }
  __syncthreads();
  const float* wb = wgt + (size_t)b * LPOOL * 16;
  float* ob = out + ((size_t)b * Csz + c) * LPOOL;
  for (int p = tid; p < LPOOL; p += 256) {
    const float* wp = wb + p * 16;
    const float* xp = &xrow[p * 8];
    float acc = 0.f;
    #pragma unroll
    for (int w = 0; w < 16; ++w) acc += xp[w] * wp[w];
    ob[p] = acc;
  }
}

// ---------------------------------------------------------------------------
extern "C" void kernel_launch(void* const* d_in, const int* in_sizes, int n_in,
                              void* d_out, int out_size, void* d_ws, size_t ws_size,
                              hipStream_t stream) {
  const float* x    = (const float*)d_in[0];
  const void*  mask = d_in[1];
  const float* W    = (const float*)d_in[2];
  const float* bias = (const float*)d_in[3];
  const float* v    = (const float*)d_in[4];
  float* out = (float*)d_out;

  char* wsb = (char*)d_ws;
  int*   flag = (int*)wsb;                                      // 256 B reserved
  float* s    = (float*)(wsb + 256);                            // B*L floats (128 KiB)
  float* wgt  = (float*)(wsb + 256 + Bsz * Lsz * sizeof(float)); // B*LPOOL*16 floats (~1 MiB)

  detect_mask<<<1, 1, 0, stream>>>((const unsigned char*)mask, flag);
  gemm_s<<<dim3(Lsz / 64, Bsz), 256, 0, stream>>>(x, W, bias, v, s);
  win_weights<<<(Bsz * LPOOL + 255) / 256, 256, 0, stream>>>(s, mask, flag, wgt);
  pool_out<<<Bsz * Csz, 256, 0, stream>>>(x, wgt, out);
}

// Round 2
// 173.496 us; speedup vs baseline: 2.6937x; 2.6937x over previous
//
#include <hip/hip_runtime.h>
#include <hip/hip_bf16.h>
#include <cmath>

#define Bsz 8
#define Csz 512
#define Lsz 4096
#define LPOOL 511
#define NEGV -1000000000.0f

typedef __attribute__((ext_vector_type(8))) short short8;
typedef __attribute__((ext_vector_type(4))) float float4v;

// ---------------------------------------------------------------------------
// Kernel 0: detect mask element width (parallel). int32 {0,1} LE => bytes at
// i%4!=0 are all zero; uint8 {0,1} => ~half nonzero. P(miss) ~ 2^-3072.
__global__ void detect_mask(const unsigned char* __restrict__ mb, int* __restrict__ flag) {
  __shared__ int sf;
  int t = threadIdx.x;
  if (t == 0) sf = 0;
  __syncthreads();
  int f = 0;
  for (int i = t; i < 4096; i += 256)
    if ((i & 3) && mb[i]) f = 1;
  if (f) atomicOr(&sf, 1);
  __syncthreads();
  if (t == 0) *flag = sf;  // 0 = int32 mask, 1 = uint8 mask
}

// ---------------------------------------------------------------------------
// Kernel A: W[d][c] fp32 -> Wt[d][c] bf16 (layout unchanged, K=c contiguous)
__global__ __launch_bounds__(256) void convert_w(const float* __restrict__ W,
                                                 __hip_bfloat16* __restrict__ Wt) {
  int i = (blockIdx.x * 256 + threadIdx.x) * 4;
  float4 wv = *(const float4*)(W + i);
  Wt[i + 0] = __float2bfloat16(wv.x);
  Wt[i + 1] = __float2bfloat16(wv.y);
  Wt[i + 2] = __float2bfloat16(wv.z);
  Wt[i + 3] = __float2bfloat16(wv.w);
}

// ---------------------------------------------------------------------------
// Kernel B: x[b][c][l] fp32 -> xT[b*L + l][c] bf16 (transpose, K=c contiguous)
__global__ __launch_bounds__(256) void transpose_x(const float* __restrict__ x,
                                                   __hip_bfloat16* __restrict__ xT) {
  __shared__ __hip_bfloat16 t[64][66];  // stride 66 bf16 = 33 banks: conflict-free
  const int b = blockIdx.z, l0 = blockIdx.x * 64, c0 = blockIdx.y * 64;
  const int tid = threadIdx.x;
  #pragma unroll
  for (int it = 0; it < 16; ++it) {
    int idx = tid + it * 256;
    int c = idx >> 6, l = idx & 63;
    t[c][l] = __float2bfloat16(x[((size_t)b * Csz + (c0 + c)) * Lsz + l0 + l]);
  }
  __syncthreads();
  #pragma unroll
  for (int it = 0; it < 16; ++it) {
    int idx = tid + it * 256;
    int l = idx >> 6, c = idx & 63;
    xT[((size_t)b * Lsz + l0 + l) * Csz + c0 + c] = t[c][l];
  }
}

// ---------------------------------------------------------------------------
// Kernel 1: s[m] = sum_d tanh( (xT·Wt^T)[m,d] + bias[d] ) * v[d]
// MFMA bf16 GEMM: block = 64 m x 512 d, K=512 in BK=32 steps. 4 waves; wave w
// covers d in [w*128,(w+1)*128) as 8 16-wide frags x 4 16-wide m frags.
__global__ __launch_bounds__(256, 2) void gemm_bf16(
    const __hip_bfloat16* __restrict__ xT, const __hip_bfloat16* __restrict__ Wt,
    const float* __restrict__ bias, const float* __restrict__ v,
    float* __restrict__ s_out) {
  __shared__ __align__(16) __hip_bfloat16 sA[64][40];    // [m][k], +8 pad (2-way=free)
  __shared__ __align__(16) __hip_bfloat16 sB[512][40];   // [d][k]
  __shared__ float s_acc[64];
  const int tid = threadIdx.x;
  const int lane = tid & 63;
  const int wave = tid >> 6;
  const int m0 = blockIdx.x * 64;
  if (tid < 64) s_acc[tid] = 0.f;

  float4v acc[4][8];
  #pragma unroll
  for (int i = 0; i < 4; ++i)
    #pragma unroll
    for (int j = 0; j < 8; ++j) acc[i][j] = (float4v)0.f;

  const int lr = lane & 15;       // n (or m) index within a 16-frag
  const int quad = lane >> 4;     // k-quad
  const int koff = quad * 8;

  float bl[8], vl[8];
  #pragma unroll
  for (int di = 0; di < 8; ++di) {
    int d = wave * 128 + di * 16 + lr;
    bl[di] = bias[d];
    vl[di] = v[d];
  }

  const int arow = tid >> 2, aseg = tid & 3;
  const __hip_bfloat16* aSrc = xT + (size_t)(m0 + arow) * Csz + aseg * 8;

  for (int c0 = 0; c0 < Csz; c0 += 32) {
    __syncthreads();
    // stage A: 64 rows x 32 k (one 16-B load per thread)
    *(short8*)(&sA[arow][aseg * 8]) = *(const short8*)(aSrc + c0);
    // stage B: 512 rows x 32 k (eight 16-B loads per thread)
    #pragma unroll
    for (int it = 0; it < 8; ++it) {
      int gi = tid + it * 256;
      int drow = gi >> 2, dseg = gi & 3;
      *(short8*)(&sB[drow][dseg * 8]) =
          *(const short8*)(Wt + (size_t)drow * Csz + c0 + dseg * 8);
    }
    __syncthreads();
    short8 af[4];
    #pragma unroll
    for (int li = 0; li < 4; ++li)
      af[li] = *(const short8*)(&sA[li * 16 + lr][koff]);
    short8 bf[8];
    #pragma unroll
    for (int di = 0; di < 8; ++di)
      bf[di] = *(const short8*)(&sB[wave * 128 + di * 16 + lr][koff]);
    #pragma unroll
    for (int li = 0; li < 4; ++li)
      #pragma unroll
      for (int di = 0; di < 8; ++di)
        acc[li][di] = __builtin_amdgcn_mfma_f32_16x16x32_bf16(af[li], bf[di], acc[li][di], 0, 0, 0);
  }

  // Epilogue: C/D layout col(d)=lane&15, row(m)=quad*4+reg. Reduce over d.
  #pragma unroll
  for (int li = 0; li < 4; ++li) {
    #pragma unroll
    for (int j = 0; j < 4; ++j) {
      float p = 0.f;
      #pragma unroll
      for (int di = 0; di < 8; ++di)
        p += tanhf(acc[li][di][j] + bl[di]) * vl[di];
      p += __shfl_xor(p, 1, 16);
      p += __shfl_xor(p, 2, 16);
      p += __shfl_xor(p, 4, 16);
      p += __shfl_xor(p, 8, 16);
      if (lr == 0) atomicAdd(&s_acc[li * 16 + quad * 4 + j], p);
    }
  }
  __syncthreads();
  if (tid < 64) s_out[m0 + tid] = s_acc[tid];  // m = b*Lsz + l: s is [b][l] flat
}

// ---------------------------------------------------------------------------
// Fallback fp32 GEMM (used only if ws too small for bf16 path)
__global__ __launch_bounds__(256) void gemm_s_f32(const float* __restrict__ x,
    const float* __restrict__ W, const float* __restrict__ bias,
    const float* __restrict__ v, float* __restrict__ s_out) {
  __shared__ float sA[32][64];
  __shared__ float sB[32][68];
  __shared__ float s_acc[64];
  const int tid = threadIdx.x;
  const int b = blockIdx.y;
  const int l0 = blockIdx.x * 64;
  if (tid < 64) s_acc[tid] = 0.0f;
  const int tx = tid & 15;
  const int ty = tid >> 4;
  const float* xb = x + ((size_t)b * Csz) * Lsz + l0;
  for (int d0 = 0; d0 < Csz; d0 += 64) {
    float acc[4][4] = {{0.f}};
    for (int c0 = 0; c0 < Csz; c0 += 32) {
      __syncthreads();
      #pragma unroll
      for (int it = 0; it < 8; ++it) {
        int idx = tid + it * 256;
        int kc = idx >> 6, ml = idx & 63;
        sA[kc][ml] = xb[(size_t)(c0 + kc) * Lsz + ml];
      }
      #pragma unroll
      for (int it = 0; it < 8; ++it) {
        int idx = tid + it * 256;
        int kc = idx & 31, dj = idx >> 5;
        sB[kc][dj] = W[(size_t)(d0 + dj) * Csz + c0 + kc];
      }
      __syncthreads();
      #pragma unroll
      for (int kc = 0; kc < 32; ++kc) {
        float4 a  = *(const float4*)(&sA[kc][tx << 2]);
        float4 w4 = *(const float4*)(&sB[kc][ty << 2]);
        acc[0][0] += a.x * w4.x; acc[0][1] += a.x * w4.y; acc[0][2] += a.x * w4.z; acc[0][3] += a.x * w4.w;
        acc[1][0] += a.y * w4.x; acc[1][1] += a.y * w4.y; acc[1][2] += a.y * w4.z; acc[1][3] += a.y * w4.w;
        acc[2][0] += a.z * w4.x; acc[2][1] += a.z * w4.y; acc[2][2] += a.z * w4.z; acc[2][3] += a.z * w4.w;
        acc[3][0] += a.w * w4.x; acc[3][1] += a.w * w4.y; acc[3][2] += a.w * w4.z; acc[3][3] += a.w * w4.w;
      }
    }
    float part[4] = {0.f, 0.f, 0.f, 0.f};
    #pragma unroll
    for (int j = 0; j < 4; ++j) {
      int d = d0 + (ty << 2) + j;
      float bj = bias[d], vj = v[d];
      #pragma unroll
      for (int i = 0; i < 4; ++i)
        part[i] += tanhf(acc[i][j] + bj) * vj;
    }
    #pragma unroll
    for (int i = 0; i < 4; ++i)
      atomicAdd(&s_acc[(tx << 2) + i], part[i]);
  }
  __syncthreads();
  if (tid < 64) s_out[(size_t)b * Lsz + l0 + tid] = s_acc[tid];
}

// ---------------------------------------------------------------------------
// Kernel 2: windowed masked softmax -> normalized weights wgt[b,p,w]
__global__ void win_weights(const float* __restrict__ s, const void* __restrict__ mask,
                            const int* __restrict__ flag, float* __restrict__ wgt) {
  int t = blockIdx.x * blockDim.x + threadIdx.x;
  if (t >= Bsz * LPOOL) return;
  int b = t / LPOOL, p = t - b * LPOOL;
  const bool u8 = (*flag != 0);
  const unsigned char* m8 = (const unsigned char*)mask;
  const int* m32 = (const int*)mask;
  float sv[16]; int mv[16];
  float mx = -3.4e38f;
  int base = b * Lsz + p * 8;
  #pragma unroll
  for (int w = 0; w < 16; ++w) {
    int mk = u8 ? (int)m8[base + w] : m32[base + w];
    float val = mk ? NEGV : s[base + w];
    sv[w] = val; mv[w] = mk;
    mx = fmaxf(mx, val);
  }
  float sum = 0.f;
  #pragma unroll
  for (int w = 0; w < 16; ++w) { sv[w] = expf(sv[w] - mx); sum += sv[w]; }
  float inv = 1.0f / sum;
  float norm = 0.f;
  #pragma unroll
  for (int w = 0; w < 16; ++w) { sv[w] = mv[w] ? 0.f : sv[w] * inv; norm += sv[w]; }
  norm = fmaxf(norm, 1e-6f);
  float rn = 1.0f / norm;
  #pragma unroll
  for (int w = 0; w < 16; ++w) wgt[t * 16 + w] = sv[w] * rn;
}

// ---------------------------------------------------------------------------
// Kernel 3: out[b,c,p] = sum_w x[b,c,8p+w] * wgt[b,p,w]. One block per (b,c).
__global__ __launch_bounds__(256) void pool_out(const float* __restrict__ x,
    const float* __restrict__ wgt, float* __restrict__ out) {
  __shared__ float xrow[Lsz];
  int bc = blockIdx.x;
  int c = bc & (Csz - 1);
  int b = bc >> 9;
  const float* xr = x + ((size_t)b * Csz + c) * Lsz;
  int tid = threadIdx.x;
  #pragma unroll
  for (int it = 0; it < 4; ++it) {
    int idx = (tid + it * 256) << 2;
    *(float4*)(&xrow[idx]) = *(const float4*)(&xr[idx]);
  }
  __syncthreads();
  const float* wb = wgt + (size_t)b * LPOOL * 16;
  float* ob = out + ((size_t)b * Csz + c) * LPOOL;
  for (int p = tid; p < LPOOL; p += 256) {
    const float* wp = wb + p * 16;
    const float* xp = &xrow[p * 8];
    float acc = 0.f;
    #pragma unroll
    for (int w = 0; w < 16; ++w) acc += xp[w] * wp[w];
    ob[p] = acc;
  }
}

// ---------------------------------------------------------------------------
extern "C" void kernel_launch(void* const* d_in, const int* in_sizes, int n_in,
                              void* d_out, int out_size, void* d_ws, size_t ws_size,
                              hipStream_t stream) {
  const float* x    = (const float*)d_in[0];
  const void*  mask = d_in[1];
  const float* W    = (const float*)d_in[2];
  const float* bias = (const float*)d_in[3];
  const float* v    = (const float*)d_in[4];
  float* out = (float*)d_out;

  char* wsb = (char*)d_ws;
  int*   flag = (int*)wsb;                                  // 256 B
  float* s    = (float*)(wsb + 256);                        // 128 KiB
  float* wgt  = (float*)(wsb + 256 + 131072);               // 256 KiB
  __hip_bfloat16* Wt = (__hip_bfloat16*)(wsb + 393472);     // 512 KiB
  __hip_bfloat16* xT = (__hip_bfloat16*)(wsb + 917760);     // 32 MiB
  const size_t NEED = 917760 + (size_t)Bsz * Lsz * Csz * 2; // ~34.5 MB

  detect_mask<<<1, 256, 0, stream>>>((const unsigned char*)mask, flag);
  if (ws_size >= NEED) {
    convert_w<<<(Csz * Csz) / 1024, 256, 0, stream>>>(W, Wt);
    transpose_x<<<dim3(Lsz / 64, Csz / 64, Bsz), 256, 0, stream>>>(x, xT);
    gemm_bf16<<<(Bsz * Lsz) / 64, 256, 0, stream>>>(xT, Wt, bias, v, s);
  } else {
    gemm_s_f32<<<dim3(Lsz / 64, Bsz), 256, 0, stream>>>(x, W, bias, v, s);
  }
  win_weights<<<(Bsz * LPOOL + 255) / 256, 256, 0, stream>>>(s, mask, flag, wgt);
  pool_out<<<Bsz * Csz, 256, 0, stream>>>(x, wgt, out);
}

// Round 3
// 160.751 us; speedup vs baseline: 2.9073x; 1.0793x over previous
//
#include <hip/hip_runtime.h>
#include <hip/hip_bf16.h>
#include <cmath>

#define Bsz 8
#define Csz 512
#define Lsz 4096
#define LPOOL 511
#define NEGV -1000000000.0f

typedef __attribute__((ext_vector_type(8))) short short8;
typedef __attribute__((ext_vector_type(4))) float float4v;

// async global->LDS, 16B per lane; LDS dest = wave-uniform base + lane*16 (HW)
__device__ __forceinline__ void gl_lds16(const __hip_bfloat16* g, void* l) {
  __builtin_amdgcn_global_load_lds(
      (const __attribute__((address_space(1))) unsigned int*)g,
      (__attribute__((address_space(3))) unsigned int*)l, 16, 0, 0);
}

// ---------------------------------------------------------------------------
// Prep: block 0 = mask-width detect; blocks 1..32 = zero s; blocks 33..160 =
// convert W[d][c] fp32 -> tiled bf16 Wts[(nt*16+ks)*512 + seg*128 + row][8].
__global__ __launch_bounds__(256) void prep(const unsigned char* __restrict__ mb,
    int* __restrict__ flag, float* __restrict__ s, const float* __restrict__ W,
    __hip_bfloat16* __restrict__ Wts) {
  const int bid = blockIdx.x, tid = threadIdx.x;
  if (bid == 0) {
    __shared__ int sf;
    if (tid == 0) sf = 0;
    __syncthreads();
    int f = 0;
    for (int i = tid; i < 4096; i += 256)
      if ((i & 3) && mb[i]) f = 1;
    if (f) atomicOr(&sf, 1);
    __syncthreads();
    if (tid == 0) *flag = sf;  // 0 = int32 mask, 1 = uint8 mask
  } else if (bid <= 32) {
    int i = (bid - 1) * 1024 + tid * 4;
    float4 z; z.x = z.y = z.z = z.w = 0.f;
    *(float4*)(s + i) = z;
  } else {
    int tg = (bid - 33) * 256 + tid;           // 32768 threads, 8 c each
    int d = tg >> 6, cg = tg & 63;
    float4 w0 = *(const float4*)(W + (size_t)d * 512 + cg * 8);
    float4 w1 = *(const float4*)(W + (size_t)d * 512 + cg * 8 + 4);
    __hip_bfloat16 hb[8];
    hb[0] = __float2bfloat16(w0.x); hb[1] = __float2bfloat16(w0.y);
    hb[2] = __float2bfloat16(w0.z); hb[3] = __float2bfloat16(w0.w);
    hb[4] = __float2bfloat16(w1.x); hb[5] = __float2bfloat16(w1.y);
    hb[6] = __float2bfloat16(w1.z); hb[7] = __float2bfloat16(w1.w);
    int nt = d >> 7, row = d & 127, ks = cg >> 2, seg = cg & 3;
    *(short8*)(Wts + (((size_t)nt * 16 + ks) * 512 + seg * 128 + row) * 8) = *(short8*)hb;
  }
}

// ---------------------------------------------------------------------------
// Transpose: x[b][c][l] fp32 -> xTs tiled bf16 [(mt*16+ks)*512 + seg*128 + row][8]
// where m = b*4096+l, mt=m>>7, row=m&127, ks=c>>5, seg=(c>>3)&3.
__global__ __launch_bounds__(256) void transpose_x(const float* __restrict__ x,
                                                   __hip_bfloat16* __restrict__ xTs) {
  __shared__ float sX[64][65];                 // 65 pitch: conflict-free both phases
  const int lt = blockIdx.x, ct = blockIdx.y, b = blockIdx.z;
  const int tid = threadIdx.x;
  const int l0 = lt * 64;
  const float* xb = x + ((size_t)b * Csz + ct * 64) * Lsz + l0;
  #pragma unroll
  for (int it = 0; it < 4; ++it) {
    int c = it * 16 + (tid >> 4);
    int l = (tid & 15) * 4;
    *(float4*)(&sX[c][l]) = *(const float4*)(xb + (size_t)c * Lsz + l);
  }
  __syncthreads();
  #pragma unroll
  for (int it = 0; it < 2; ++it) {
    int u = it * 256 + tid;
    int cg = u >> 6, ll = u & 63;              // wave-uniform cg, lane = ll
    __hip_bfloat16 hb[8];
    #pragma unroll
    for (int j = 0; j < 8; ++j)
      hb[j] = __float2bfloat16(sX[cg * 8 + j][ll]);
    int m = b * Lsz + l0 + ll;
    int mt = m >> 7, row = m & 127;
    int cglob = ct * 64 + cg * 8;
    int ks = cglob >> 5, seg = (cglob >> 3) & 3;
    *(short8*)(xTs + (((size_t)mt * 16 + ks) * 512 + seg * 128 + row) * 8) = *(short8*)hb;
  }
}

// ---------------------------------------------------------------------------
// GEMM: s[m] += sum_{d in n-tile} tanh((xT.WtT)[m,d]+bias[d])*v[d]
// 128m x 128n block, 4 waves (2x2), wave tile 64x64 = 4x4 frags of 16x16x32.
// Staging: global_load_lds 16B, fully coalesced (tiled global layout);
// LDS seg-major => frag reads are contiguous 16B units (2-way = free).
__global__ __launch_bounds__(256, 2) void gemm_bf16(
    const __hip_bfloat16* __restrict__ xTs, const __hip_bfloat16* __restrict__ Wts,
    const float* __restrict__ bias, const float* __restrict__ v,
    float* __restrict__ s) {
  __shared__ short8 sAv[512];                  // [seg][row] 16B units, 8 KB
  __shared__ short8 sBv[512];
  const int tid = threadIdx.x;
  const int lane = tid & 63, wave = tid >> 6;
  const int lr = lane & 15, quad = lane >> 4;
  const int mh = wave >> 1, nh = wave & 1;
  const int mt = blockIdx.x, nt = blockIdx.y;
  const __hip_bfloat16* aT = xTs + (size_t)mt * 65536;  // 16 ks * 512 units * 8
  const __hip_bfloat16* bT = Wts + (size_t)nt * 65536;

  float bl[4], vl[4];
  #pragma unroll
  for (int nf = 0; nf < 4; ++nf) {
    int n = nt * 128 + nh * 64 + nf * 16 + lr;
    bl[nf] = bias[n]; vl[nf] = v[n];
  }

  float4v acc[4][4];
  #pragma unroll
  for (int i = 0; i < 4; ++i)
    #pragma unroll
    for (int j = 0; j < 4; ++j) acc[i][j] = (float4v)0.f;

  for (int ks = 0; ks < 16; ++ks) {
    __syncthreads();
    const __hip_bfloat16* ga = aT + ks * 4096 + (wave * 64 + lane) * 8;
    const __hip_bfloat16* gb = bT + ks * 4096 + (wave * 64 + lane) * 8;
    gl_lds16(ga,        &sAv[wave * 64]);
    gl_lds16(ga + 2048, &sAv[256 + wave * 64]);
    gl_lds16(gb,        &sBv[wave * 64]);
    gl_lds16(gb + 2048, &sBv[256 + wave * 64]);
    __syncthreads();
    short8 af[4], bfr[4];
    #pragma unroll
    for (int mf = 0; mf < 4; ++mf)
      af[mf] = sAv[quad * 128 + mh * 64 + mf * 16 + lr];
    #pragma unroll
    for (int nf = 0; nf < 4; ++nf)
      bfr[nf] = sBv[quad * 128 + nh * 64 + nf * 16 + lr];
    #pragma unroll
    for (int mf = 0; mf < 4; ++mf)
      #pragma unroll
      for (int nf = 0; nf < 4; ++nf)
        acc[mf][nf] = __builtin_amdgcn_mfma_f32_16x16x32_bf16(af[mf], bfr[nf], acc[mf][nf], 0, 0, 0);
  }

  // Epilogue: C/D 16x16: n = lane&15, m = quad*4+reg. Reduce over n, atomic to s.
  #pragma unroll
  for (int mf = 0; mf < 4; ++mf) {
    #pragma unroll
    for (int reg = 0; reg < 4; ++reg) {
      float p = 0.f;
      #pragma unroll
      for (int nf = 0; nf < 4; ++nf)
        p += tanhf(acc[mf][nf][reg] + bl[nf]) * vl[nf];
      p += __shfl_xor(p, 1, 16);
      p += __shfl_xor(p, 2, 16);
      p += __shfl_xor(p, 4, 16);
      p += __shfl_xor(p, 8, 16);
      if (lr == 0)
        atomicAdd(&s[mt * 128 + mh * 64 + mf * 16 + quad * 4 + reg], p);
    }
  }
}

// ---------------------------------------------------------------------------
// Fallback fp32 GEMM (only if ws too small for bf16 path)
__global__ __launch_bounds__(256) void gemm_s_f32(const float* __restrict__ x,
    const float* __restrict__ W, const float* __restrict__ bias,
    const float* __restrict__ v, float* __restrict__ s_out) {
  __shared__ float sA[32][64];
  __shared__ float sB[32][68];
  __shared__ float s_acc[64];
  const int tid = threadIdx.x;
  const int b = blockIdx.y;
  const int l0 = blockIdx.x * 64;
  if (tid < 64) s_acc[tid] = 0.0f;
  const int tx = tid & 15;
  const int ty = tid >> 4;
  const float* xb = x + ((size_t)b * Csz) * Lsz + l0;
  for (int d0 = 0; d0 < Csz; d0 += 64) {
    float acc[4][4] = {{0.f}};
    for (int c0 = 0; c0 < Csz; c0 += 32) {
      __syncthreads();
      #pragma unroll
      for (int it = 0; it < 8; ++it) {
        int idx = tid + it * 256;
        int kc = idx >> 6, ml = idx & 63;
        sA[kc][ml] = xb[(size_t)(c0 + kc) * Lsz + ml];
      }
      #pragma unroll
      for (int it = 0; it < 8; ++it) {
        int idx = tid + it * 256;
        int kc = idx & 31, dj = idx >> 5;
        sB[kc][dj] = W[(size_t)(d0 + dj) * Csz + c0 + kc];
      }
      __syncthreads();
      #pragma unroll
      for (int kc = 0; kc < 32; ++kc) {
        float4 a  = *(const float4*)(&sA[kc][tx << 2]);
        float4 w4 = *(const float4*)(&sB[kc][ty << 2]);
        acc[0][0] += a.x * w4.x; acc[0][1] += a.x * w4.y; acc[0][2] += a.x * w4.z; acc[0][3] += a.x * w4.w;
        acc[1][0] += a.y * w4.x; acc[1][1] += a.y * w4.y; acc[1][2] += a.y * w4.z; acc[1][3] += a.y * w4.w;
        acc[2][0] += a.z * w4.x; acc[2][1] += a.z * w4.y; acc[2][2] += a.z * w4.z; acc[2][3] += a.z * w4.w;
        acc[3][0] += a.w * w4.x; acc[3][1] += a.w * w4.y; acc[3][2] += a.w * w4.z; acc[3][3] += a.w * w4.w;
      }
    }
    float part[4] = {0.f, 0.f, 0.f, 0.f};
    #pragma unroll
    for (int j = 0; j < 4; ++j) {
      int d = d0 + (ty << 2) + j;
      float bj = bias[d], vj = v[d];
      #pragma unroll
      for (int i = 0; i < 4; ++i)
        part[i] += tanhf(acc[i][j] + bj) * vj;
    }
    #pragma unroll
    for (int i = 0; i < 4; ++i)
      atomicAdd(&s_acc[(tx << 2) + i], part[i]);
  }
  __syncthreads();
  if (tid < 64) s_out[(size_t)b * Lsz + l0 + tid] = s_acc[tid];
}

// ---------------------------------------------------------------------------
// Windowed masked softmax -> normalized weights wgt[b,p,w]
__global__ void win_weights(const float* __restrict__ s, const void* __restrict__ mask,
                            const int* __restrict__ flag, float* __restrict__ wgt) {
  int t = blockIdx.x * blockDim.x + threadIdx.x;
  if (t >= Bsz * LPOOL) return;
  int b = t / LPOOL, p = t - b * LPOOL;
  const bool u8 = (*flag != 0);
  const unsigned char* m8 = (const unsigned char*)mask;
  const int* m32 = (const int*)mask;
  float sv[16]; int mv[16];
  float mx = -3.4e38f;
  int base = b * Lsz + p * 8;
  #pragma unroll
  for (int w = 0; w < 16; ++w) {
    int mk = u8 ? (int)m8[base + w] : m32[base + w];
    float val = mk ? NEGV : s[base + w];
    sv[w] = val; mv[w] = mk;
    mx = fmaxf(mx, val);
  }
  float sum = 0.f;
  #pragma unroll
  for (int w = 0; w < 16; ++w) { sv[w] = expf(sv[w] - mx); sum += sv[w]; }
  float inv = 1.0f / sum;
  float norm = 0.f;
  #pragma unroll
  for (int w = 0; w < 16; ++w) { sv[w] = mv[w] ? 0.f : sv[w] * inv; norm += sv[w]; }
  norm = fmaxf(norm, 1e-6f);
  float rn = 1.0f / norm;
  #pragma unroll
  for (int w = 0; w < 16; ++w) wgt[t * 16 + w] = sv[w] * rn;
}

// ---------------------------------------------------------------------------
// out[b,c,p] = sum_w x[b,c,8p+w] * wgt[b,p,w]. One block per (b,c).
__global__ __launch_bounds__(256) void pool_out(const float* __restrict__ x,
    const float* __restrict__ wgt, float* __restrict__ out) {
  __shared__ float xrow[Lsz];
  int bc = blockIdx.x;
  int c = bc & (Csz - 1);
  int b = bc >> 9;
  const float* xr = x + ((size_t)b * Csz + c) * Lsz;
  int tid = threadIdx.x;
  #pragma unroll
  for (int it = 0; it < 4; ++it) {
    int idx = (tid + it * 256) << 2;
    *(float4*)(&xrow[idx]) = *(const float4*)(&xr[idx]);
  }
  __syncthreads();
  const float* wb = wgt + (size_t)b * LPOOL * 16;
  float* ob = out + ((size_t)b * Csz + c) * LPOOL;
  for (int p = tid; p < LPOOL; p += 256) {
    const float4* wp = (const float4*)(wb + p * 16);
    const float4* xp = (const float4*)(&xrow[p * 8]);
    float acc = 0.f;
    #pragma unroll
    for (int q = 0; q < 4; ++q) {
      float4 wv = wp[q], xv = xp[q];
      acc += xv.x * wv.x + xv.y * wv.y + xv.z * wv.z + xv.w * wv.w;
    }
    ob[p] = acc;
  }
}

// ---------------------------------------------------------------------------
extern "C" void kernel_launch(void* const* d_in, const int* in_sizes, int n_in,
                              void* d_out, int out_size, void* d_ws, size_t ws_size,
                              hipStream_t stream) {
  const float* x    = (const float*)d_in[0];
  const void*  mask = d_in[1];
  const float* W    = (const float*)d_in[2];
  const float* bias = (const float*)d_in[3];
  const float* v    = (const float*)d_in[4];
  float* out = (float*)d_out;

  char* wsb = (char*)d_ws;
  int*   flag = (int*)wsb;                              // 256 B
  float* s    = (float*)(wsb + 256);                    // 131072 B
  float* wgt  = (float*)(wsb + 131328);                 // 261632 B
  __hip_bfloat16* Wts = (__hip_bfloat16*)(wsb + 393216);// 524288 B
  __hip_bfloat16* xTs = (__hip_bfloat16*)(wsb + 917504);// 33554432 B
  const size_t NEED = 917504 + 33554432;

  if (ws_size >= NEED) {
    prep<<<161, 256, 0, stream>>>((const unsigned char*)mask, flag, s, W, Wts);
    transpose_x<<<dim3(Lsz / 64, Csz / 64, Bsz), 256, 0, stream>>>(x, xTs);
    gemm_bf16<<<dim3(256, 4), 256, 0, stream>>>(xTs, Wts, bias, v, s);
  } else {
    prep<<<1, 256, 0, stream>>>((const unsigned char*)mask, flag, s, W, Wts);
    gemm_s_f32<<<dim3(Lsz / 64, Bsz), 256, 0, stream>>>(x, W, bias, v, s);
  }
  win_weights<<<(Bsz * LPOOL + 255) / 256, 256, 0, stream>>>(s, mask, flag, wgt);
  pool_out<<<Bsz * Csz, 256, 0, stream>>>(x, wgt, out);
}

// Round 4
// 158.824 us; speedup vs baseline: 2.9426x; 1.0121x over previous
//
#include <hip/hip_runtime.h>
#include <hip/hip_bf16.h>
#include <cmath>

#define Bsz 8
#define Csz 512
#define Lsz 4096
#define LPOOL 511
#define NEGV -1000000000.0f

typedef __attribute__((ext_vector_type(8))) short short8;
typedef __attribute__((ext_vector_type(4))) float float4v;

__device__ __forceinline__ float bf2f(short u) {
  unsigned int x = ((unsigned int)(unsigned short)u) << 16;
  return __builtin_bit_cast(float, x);
}

// async global->LDS, 16B per lane; LDS dest = wave-uniform base + lane*16 (HW)
__device__ __forceinline__ void gl_lds16(const __hip_bfloat16* g, void* l) {
  __builtin_amdgcn_global_load_lds(
      (const __attribute__((address_space(1))) unsigned int*)g,
      (__attribute__((address_space(3))) unsigned int*)l, 16, 0, 0);
}

// ---------------------------------------------------------------------------
// stage1: flat grid 4096+161 blocks.
//  bid<4096: transpose tile -> xTs (tiled bf16 for MFMA) AND xbf (natural bf16)
//  bid>=4096: prep jobs: mask-width detect / zero s / convert W -> Wts tiled.
__global__ __launch_bounds__(256) void stage1(const float* __restrict__ x,
    __hip_bfloat16* __restrict__ xTs, __hip_bfloat16* __restrict__ xbf,
    const unsigned char* __restrict__ mb, int* __restrict__ flag,
    float* __restrict__ s, const float* __restrict__ W,
    __hip_bfloat16* __restrict__ Wts) {
  const int tid = threadIdx.x;
  const int bid = blockIdx.x;
  if (bid < 4096) {
    __shared__ float sX[64][65];               // 65 pitch: conflict-free
    const int lt = bid & 63, ct = (bid >> 6) & 7, b = bid >> 9;
    const int l0 = lt * 64;
    const float* xb = x + ((size_t)b * Csz + ct * 64) * Lsz + l0;
    #pragma unroll
    for (int it = 0; it < 4; ++it) {
      int c = it * 16 + (tid >> 4);
      int l = (tid & 15) * 4;
      *(float4*)(&sX[c][l]) = *(const float4*)(xb + (size_t)c * Lsz + l);
    }
    __syncthreads();
    // tiled layout for MFMA staging
    #pragma unroll
    for (int it = 0; it < 2; ++it) {
      int u = it * 256 + tid;
      int cg = u >> 6, ll = u & 63;
      __hip_bfloat16 hb[8];
      #pragma unroll
      for (int j = 0; j < 8; ++j)
        hb[j] = __float2bfloat16(sX[cg * 8 + j][ll]);
      int m = b * Lsz + l0 + ll;
      int mt = m >> 7, row = m & 127;
      int cglob = ct * 64 + cg * 8;
      int ks = cglob >> 5, seg = (cglob >> 3) & 3;
      *(short8*)(xTs + (((size_t)mt * 16 + ks) * 512 + seg * 128 + row) * 8) = *(short8*)hb;
    }
    // natural layout bf16 copy for pool
    #pragma unroll
    for (int it = 0; it < 2; ++it) {
      int u = it * 256 + tid;
      int cg = u >> 3, lseg = u & 7;
      __hip_bfloat16 hb[8];
      #pragma unroll
      for (int j = 0; j < 8; ++j)
        hb[j] = __float2bfloat16(sX[cg][lseg * 8 + j]);
      *(short8*)(xbf + ((size_t)b * Csz + ct * 64 + cg) * Lsz + l0 + lseg * 8) = *(short8*)hb;
    }
  } else {
    const int pb = bid - 4096;
    if (pb == 0) {
      __shared__ int sf;
      if (tid == 0) sf = 0;
      __syncthreads();
      int f = 0;
      for (int i = tid; i < 4096; i += 256)
        if ((i & 3) && mb[i]) f = 1;
      if (f) atomicOr(&sf, 1);
      __syncthreads();
      if (tid == 0) *flag = sf;  // 0 = int32 mask, 1 = uint8 mask
    } else if (pb <= 32) {
      int i = (pb - 1) * 1024 + tid * 4;
      float4 z; z.x = z.y = z.z = z.w = 0.f;
      *(float4*)(s + i) = z;
    } else {
      int tg = (pb - 33) * 256 + tid;
      int d = tg >> 6, cg = tg & 63;
      float4 w0 = *(const float4*)(W + (size_t)d * 512 + cg * 8);
      float4 w1 = *(const float4*)(W + (size_t)d * 512 + cg * 8 + 4);
      __hip_bfloat16 hb[8];
      hb[0] = __float2bfloat16(w0.x); hb[1] = __float2bfloat16(w0.y);
      hb[2] = __float2bfloat16(w0.z); hb[3] = __float2bfloat16(w0.w);
      hb[4] = __float2bfloat16(w1.x); hb[5] = __float2bfloat16(w1.y);
      hb[6] = __float2bfloat16(w1.z); hb[7] = __float2bfloat16(w1.w);
      int nt = d >> 7, row = d & 127, ks = cg >> 2, seg = cg & 3;
      *(short8*)(Wts + (((size_t)nt * 16 + ks) * 512 + seg * 128 + row) * 8) = *(short8*)hb;
    }
  }
}

// ---------------------------------------------------------------------------
// GEMM: s[m] += sum_{d in n-tile} tanh((xT.WtT)[m,d]+bias[d])*v[d]
// 128m x 128n block, 4 waves (2x2), wave tile 64x64 = 4x4 frags of 16x16x32.
__global__ __launch_bounds__(256, 2) void gemm_bf16(
    const __hip_bfloat16* __restrict__ xTs, const __hip_bfloat16* __restrict__ Wts,
    const float* __restrict__ bias, const float* __restrict__ v,
    float* __restrict__ s) {
  __shared__ short8 sAv[512];                  // [seg][row] 16B units, 8 KB
  __shared__ short8 sBv[512];
  const int tid = threadIdx.x;
  const int lane = tid & 63, wave = tid >> 6;
  const int lr = lane & 15, quad = lane >> 4;
  const int mh = wave >> 1, nh = wave & 1;
  const int mt = blockIdx.x, nt = blockIdx.y;
  const __hip_bfloat16* aT = xTs + (size_t)mt * 65536;
  const __hip_bfloat16* bT = Wts + (size_t)nt * 65536;

  float bl[4], vl[4];
  #pragma unroll
  for (int nf = 0; nf < 4; ++nf) {
    int n = nt * 128 + nh * 64 + nf * 16 + lr;
    bl[nf] = bias[n]; vl[nf] = v[n];
  }

  float4v acc[4][4];
  #pragma unroll
  for (int i = 0; i < 4; ++i)
    #pragma unroll
    for (int j = 0; j < 4; ++j) acc[i][j] = (float4v)0.f;

  for (int ks = 0; ks < 16; ++ks) {
    __syncthreads();
    const __hip_bfloat16* ga = aT + ks * 4096 + (wave * 64 + lane) * 8;
    const __hip_bfloat16* gb = bT + ks * 4096 + (wave * 64 + lane) * 8;
    gl_lds16(ga,        &sAv[wave * 64]);
    gl_lds16(ga + 2048, &sAv[256 + wave * 64]);
    gl_lds16(gb,        &sBv[wave * 64]);
    gl_lds16(gb + 2048, &sBv[256 + wave * 64]);
    __syncthreads();
    short8 af[4], bfr[4];
    #pragma unroll
    for (int mf = 0; mf < 4; ++mf)
      af[mf] = sAv[quad * 128 + mh * 64 + mf * 16 + lr];
    #pragma unroll
    for (int nf = 0; nf < 4; ++nf)
      bfr[nf] = sBv[quad * 128 + nh * 64 + nf * 16 + lr];
    #pragma unroll
    for (int mf = 0; mf < 4; ++mf)
      #pragma unroll
      for (int nf = 0; nf < 4; ++nf)
        acc[mf][nf] = __builtin_amdgcn_mfma_f32_16x16x32_bf16(af[mf], bfr[nf], acc[mf][nf], 0, 0, 0);
  }

  // Epilogue: C/D 16x16: n = lane&15, m = quad*4+reg. Reduce over n, atomic to s.
  #pragma unroll
  for (int mf = 0; mf < 4; ++mf) {
    #pragma unroll
    for (int reg = 0; reg < 4; ++reg) {
      float p = 0.f;
      #pragma unroll
      for (int nf = 0; nf < 4; ++nf)
        p += tanhf(acc[mf][nf][reg] + bl[nf]) * vl[nf];
      p += __shfl_xor(p, 1, 16);
      p += __shfl_xor(p, 2, 16);
      p += __shfl_xor(p, 4, 16);
      p += __shfl_xor(p, 8, 16);
      if (lr == 0)
        atomicAdd(&s[mt * 128 + mh * 64 + mf * 16 + quad * 4 + reg], p);
    }
  }
}

// ---------------------------------------------------------------------------
// pool2: fused windowed-softmax + pooling. Block = (8 p's) x (all 512 c) for
// one b. Softmax by 8 threads into LDS; then 32c x 8p threads, 16 c-iters,
// reading natural-layout bf16 x (two 16B loads per window, dense coalescing).
__global__ __launch_bounds__(256) void pool2(const __hip_bfloat16* __restrict__ xbf,
    const float* __restrict__ s, const void* __restrict__ mask,
    const int* __restrict__ flag, float* __restrict__ out) {
  __shared__ float wl[8][17];                  // 17 pitch: conflict-free
  const int t = threadIdx.x;
  const int p0 = blockIdx.x * 8, b = blockIdx.y;
  if (t < 8 && p0 + t < LPOOL) {
    const int p = p0 + t;
    const bool u8 = (*flag != 0);
    const unsigned char* m8 = (const unsigned char*)mask;
    const int* m32 = (const int*)mask;
    const int base = b * Lsz + p * 8;
    float sv[16]; int mv[16];
    float mx = -3.4e38f;
    #pragma unroll
    for (int w = 0; w < 16; ++w) {
      int mk = u8 ? (int)m8[base + w] : m32[base + w];
      float val = mk ? NEGV : s[base + w];
      sv[w] = val; mv[w] = mk;
      mx = fmaxf(mx, val);
    }
    float sum = 0.f;
    #pragma unroll
    for (int w = 0; w < 16; ++w) { sv[w] = expf(sv[w] - mx); sum += sv[w]; }
    float inv = 1.0f / sum;
    float norm = 0.f;
    #pragma unroll
    for (int w = 0; w < 16; ++w) { sv[w] = mv[w] ? 0.f : sv[w] * inv; norm += sv[w]; }
    norm = fmaxf(norm, 1e-6f);
    float rn = 1.0f / norm;
    #pragma unroll
    for (int w = 0; w < 16; ++w) wl[t][w] = sv[w] * rn;
  }
  __syncthreads();
  const int ci = t >> 3, pi = t & 7;
  const int p = p0 + pi;
  if (p >= LPOOL) return;
  float wr[16];
  #pragma unroll
  for (int w = 0; w < 16; ++w) wr[w] = wl[pi][w];
  #pragma unroll 4
  for (int it = 0; it < 16; ++it) {
    int c = it * 32 + ci;
    const __hip_bfloat16* xp = xbf + ((size_t)b * Csz + c) * Lsz + 8 * p;
    short8 lo = *(const short8*)xp;
    short8 hi = *(const short8*)(xp + 8);
    float acc = 0.f;
    #pragma unroll
    for (int j = 0; j < 8; ++j)
      acc += bf2f(lo[j]) * wr[j] + bf2f(hi[j]) * wr[8 + j];
    out[((size_t)b * Csz + c) * LPOOL + p] = acc;
  }
}

// ---------------------------------------------------------------------------
// Fallback path kernels (only if ws too small for bf16 path)
__global__ void detect_mask(const unsigned char* __restrict__ mb, int* __restrict__ flag) {
  __shared__ int sf;
  int t = threadIdx.x;
  if (t == 0) sf = 0;
  __syncthreads();
  int f = 0;
  for (int i = t; i < 4096; i += 256)
    if ((i & 3) && mb[i]) f = 1;
  if (f) atomicOr(&sf, 1);
  __syncthreads();
  if (t == 0) *flag = sf;
}

__global__ __launch_bounds__(256) void gemm_s_f32(const float* __restrict__ x,
    const float* __restrict__ W, const float* __restrict__ bias,
    const float* __restrict__ v, float* __restrict__ s_out) {
  __shared__ float sA[32][64];
  __shared__ float sB[32][68];
  __shared__ float s_acc[64];
  const int tid = threadIdx.x;
  const int b = blockIdx.y;
  const int l0 = blockIdx.x * 64;
  if (tid < 64) s_acc[tid] = 0.0f;
  const int tx = tid & 15;
  const int ty = tid >> 4;
  const float* xb = x + ((size_t)b * Csz) * Lsz + l0;
  for (int d0 = 0; d0 < Csz; d0 += 64) {
    float acc[4][4] = {{0.f}};
    for (int c0 = 0; c0 < Csz; c0 += 32) {
      __syncthreads();
      #pragma unroll
      for (int it = 0; it < 8; ++it) {
        int idx = tid + it * 256;
        int kc = idx >> 6, ml = idx & 63;
        sA[kc][ml] = xb[(size_t)(c0 + kc) * Lsz + ml];
      }
      #pragma unroll
      for (int it = 0; it < 8; ++it) {
        int idx = tid + it * 256;
        int kc = idx & 31, dj = idx >> 5;
        sB[kc][dj] = W[(size_t)(d0 + dj) * Csz + c0 + kc];
      }
      __syncthreads();
      #pragma unroll
      for (int kc = 0; kc < 32; ++kc) {
        float4 a  = *(const float4*)(&sA[kc][tx << 2]);
        float4 w4 = *(const float4*)(&sB[kc][ty << 2]);
        acc[0][0] += a.x * w4.x; acc[0][1] += a.x * w4.y; acc[0][2] += a.x * w4.z; acc[0][3] += a.x * w4.w;
        acc[1][0] += a.y * w4.x; acc[1][1] += a.y * w4.y; acc[1][2] += a.y * w4.z; acc[1][3] += a.y * w4.w;
        acc[2][0] += a.z * w4.x; acc[2][1] += a.z * w4.y; acc[2][2] += a.z * w4.z; acc[2][3] += a.z * w4.w;
        acc[3][0] += a.w * w4.x; acc[3][1] += a.w * w4.y; acc[3][2] += a.w * w4.z; acc[3][3] += a.w * w4.w;
      }
    }
    float part[4] = {0.f, 0.f, 0.f, 0.f};
    #pragma unroll
    for (int j = 0; j < 4; ++j) {
      int d = d0 + (ty << 2) + j;
      float bj = bias[d], vj = v[d];
      #pragma unroll
      for (int i = 0; i < 4; ++i)
        part[i] += tanhf(acc[i][j] + bj) * vj;
    }
    #pragma unroll
    for (int i = 0; i < 4; ++i)
      atomicAdd(&s_acc[(tx << 2) + i], part[i]);
  }
  __syncthreads();
  if (tid < 64) s_out[(size_t)b * Lsz + l0 + tid] = s_acc[tid];
}

__global__ void win_weights(const float* __restrict__ s, const void* __restrict__ mask,
                            const int* __restrict__ flag, float* __restrict__ wgt) {
  int t = blockIdx.x * blockDim.x + threadIdx.x;
  if (t >= Bsz * LPOOL) return;
  int b = t / LPOOL, p = t - b * LPOOL;
  const bool u8 = (*flag != 0);
  const unsigned char* m8 = (const unsigned char*)mask;
  const int* m32 = (const int*)mask;
  float sv[16]; int mv[16];
  float mx = -3.4e38f;
  int base = b * Lsz + p * 8;
  #pragma unroll
  for (int w = 0; w < 16; ++w) {
    int mk = u8 ? (int)m8[base + w] : m32[base + w];
    float val = mk ? NEGV : s[base + w];
    sv[w] = val; mv[w] = mk;
    mx = fmaxf(mx, val);
  }
  float sum = 0.f;
  #pragma unroll
  for (int w = 0; w < 16; ++w) { sv[w] = expf(sv[w] - mx); sum += sv[w]; }
  float inv = 1.0f / sum;
  float norm = 0.f;
  #pragma unroll
  for (int w = 0; w < 16; ++w) { sv[w] = mv[w] ? 0.f : sv[w] * inv; norm += sv[w]; }
  norm = fmaxf(norm, 1e-6f);
  float rn = 1.0f / norm;
  #pragma unroll
  for (int w = 0; w < 16; ++w) wgt[t * 16 + w] = sv[w] * rn;
}

__global__ __launch_bounds__(256) void pool_out(const float* __restrict__ x,
    const float* __restrict__ wgt, float* __restrict__ out) {
  __shared__ float xrow[Lsz];
  int bc = blockIdx.x;
  int c = bc & (Csz - 1);
  int b = bc >> 9;
  const float* xr = x + ((size_t)b * Csz + c) * Lsz;
  int tid = threadIdx.x;
  #pragma unroll
  for (int it = 0; it < 4; ++it) {
    int idx = (tid + it * 256) << 2;
    *(float4*)(&xrow[idx]) = *(const float4*)(&xr[idx]);
  }
  __syncthreads();
  const float* wb = wgt + (size_t)b * LPOOL * 16;
  float* ob = out + ((size_t)b * Csz + c) * LPOOL;
  for (int p = tid; p < LPOOL; p += 256) {
    const float4* wp = (const float4*)(wb + p * 16);
    const float4* xp = (const float4*)(&xrow[p * 8]);
    float acc = 0.f;
    #pragma unroll
    for (int q = 0; q < 4; ++q) {
      float4 wv = wp[q], xv = xp[q];
      acc += xv.x * wv.x + xv.y * wv.y + xv.z * wv.z + xv.w * wv.w;
    }
    ob[p] = acc;
  }
}

// ---------------------------------------------------------------------------
extern "C" void kernel_launch(void* const* d_in, const int* in_sizes, int n_in,
                              void* d_out, int out_size, void* d_ws, size_t ws_size,
                              hipStream_t stream) {
  const float* x    = (const float*)d_in[0];
  const void*  mask = d_in[1];
  const float* W    = (const float*)d_in[2];
  const float* bias = (const float*)d_in[3];
  const float* v    = (const float*)d_in[4];
  float* out = (float*)d_out;

  char* wsb = (char*)d_ws;
  int*   flag = (int*)wsb;                                   // 256 B
  float* s    = (float*)(wsb + 256);                         // 131072 B
  float* wgt  = (float*)(wsb + 131328);                      // 261632 B (fallback only)
  __hip_bfloat16* Wts = (__hip_bfloat16*)(wsb + 393216);     // 524288 B
  __hip_bfloat16* xTs = (__hip_bfloat16*)(wsb + 917504);     // 32 MiB
  __hip_bfloat16* xbf = (__hip_bfloat16*)(wsb + 917504 + 33554432); // 32 MiB
  const size_t NEED = 917504 + 33554432 + 33554432;

  if (ws_size >= NEED) {
    stage1<<<4096 + 161, 256, 0, stream>>>(x, xTs, xbf,
        (const unsigned char*)mask, flag, s, W, Wts);
    gemm_bf16<<<dim3(256, 4), 256, 0, stream>>>(xTs, Wts, bias, v, s);
    pool2<<<dim3(64, Bsz), 256, 0, stream>>>(xbf, s, mask, flag, out);
  } else {
    detect_mask<<<1, 256, 0, stream>>>((const unsigned char*)mask, flag);
    gemm_s_f32<<<dim3(Lsz / 64, Bsz), 256, 0, stream>>>(x, W, bias, v, s);
    win_weights<<<(Bsz * LPOOL + 255) / 256, 256, 0, stream>>>(s, mask, flag, wgt);
    pool_out<<<Bsz * Csz, 256, 0, stream>>>(x, wgt, out);
  }
}